// Round 10
// baseline (462.322 us; speedup 1.0000x reference)
//
#include <hip/hip_runtime.h>

// Greedy NMS: keep[i] = !any(keep[j] for j in knn[i] if j < i)
//
// Round-22: single-word-spin detection + LDS fanout. R19/R21 showed the
// chain term D+E ~= 4.8 us/hop binds (above the phase-1 bound (P+E)/8);
// two rounds of cheaper consumer polling each bought only ~0.5 us ->
// the cost is the DETECT PATH: ~2K survivor threads each polling several
// LLC words per pass (0.3-0.5 us RT quanta, compounded by slowest-lane
// publish gating). Changes vs R21:
//   - lm (u32 LDS mirror) REPLACED by lmq (u64 LDS mirror, in-band valid
//     bit -- value+flag in one atom, no ordering needed).
//   - wave 0's 64 lanes each own <=8 window words and spin on ONE global
//     word at a time (tightest detect), ds-writing arrivals into lmq.
//   - survivor threads resolve ext preds against lmq ONLY (LDS pass
//     interval ~0.1 us); eovf rescans also LDS-only. LLC polling traffic
//     collapses to 64 single-word spins.
//   - per-wave publish moved INSIDE the loop: a wave publishes the moment
//     all its 64 lanes decide (wave 0 keeps copying after publishing).
//   - lmq[ws..we) zeroed before the loop (uninit LDS must not fake valid).
// Everything else (classification, phase-1 trigger/copy/probe, ext masks,
// s_sleep forms, outputs) = R21 verbatim.
// Geometry: CHUNK=2048, QRT=2, NCH=74, WCH=8, ICAP=6, ECAP=16.
//
// Output encoding (validated round 4): INT32.
//   d_out[0..M)        : kept flags, 1 / 0
//   d_out[M..M+M*64)   : kept_knn, idx or 150000 (tail doubles as u64 word
//                        scratch, owned by block 73 which never publishes)
// d_ws[0..3]: progress counter (zeroed by init kernel each call)

#define M_ROWS 150000
#define KNN    64
#define BLK    1024
#define QRT    2
#define CHUNK  (BLK * QRT)                        // 2048
#define NCH    ((M_ROWS + CHUNK - 1) / CHUNK)     // 74
#define ICAP   6
#define ECAP   16
#define WCH    8                                  // exl window, chunks (16384 rows)
#define W64PC  (CHUNK / 32)                       // 64 published u64 words/chunk
#define LMW    (((NCH - 1) * CHUNK) / 32)         // 4672 window words (u64 mirror)
#define NBMG   ((NCH - 1) * W64PC)                // 4672 published u64 words
#define OUT_INTS (M_ROWS + M_ROWS * KNN)
#define BMG_INT_OFF (OUT_INTS - NBMG * 2)         // 8B-aligned; rows >= 149854
#define VALIDB (1ull << 32)

__global__ void init_ws_kernel(unsigned int* progress, int* out) {
  const int i = blockIdx.x * blockDim.x + threadIdx.x;
  unsigned long long* bmg64 = (unsigned long long*)(out + BMG_INT_OFF);
  if (i < NBMG) bmg64[i] = 0ull;                  // clear stale valid bits
  if (i == 0) *progress = 0u;
}

// reload a row and probe preds j in [lo, hi) against the LDS u64 mirror
__device__ __forceinline__ bool probe_reload(const int* __restrict__ rp,
                                             const unsigned long long* lmq,
                                             int lo, int hi) {
  bool s = false;
#pragma unroll
  for (int u = 0; u < 16; ++u) {
    int4 d = ((const int4*)rp)[u];
    int js[4] = {d.x, d.y, d.z, d.w};
#pragma unroll
    for (int m = 0; m < 4; ++m) {
      int j = js[m];
      if (j >= lo && j < hi && ((lmq[j >> 5] >> (j & 31)) & 1ull)) s = true;
    }
  }
  return s;
}

__global__ __launch_bounds__(BLK) void nms_chain_kernel(
    const int* __restrict__ knn,
    int* __restrict__ out,
    unsigned int* __restrict__ progress)
{
  const int b    = blockIdx.x;
  const int t    = threadIdx.x;
  const int base = b * CHUNK;
  const int winb = (b > WCH) ? (base - WCH * CHUNK) : 0;   // exl window base

  unsigned long long* bmg64 = (unsigned long long*)(out + BMG_INT_OFF);

  __shared__ unsigned char      st[CHUNK];        // 0 unk, 1 kept, 2 supp
  __shared__ unsigned short     il[ICAP][CHUNK];  // TRANSPOSED: conflict-free
  __shared__ unsigned short     exl[ECAP][CHUNK]; // TRANSPOSED: conflict-free
  __shared__ unsigned long long lmq[LMW];         // u64 mirror, in-band valid
  __shared__ unsigned int       sh_p;

  int  rowq[QRT];
  bool vq[QRT], ovf[QRT], eovf[QRT], supp[QRT];
  int  ic[QRT], ec[QRT];

#pragma unroll
  for (int q = 0; q < QRT; ++q) {
    rowq[q] = base + q * BLK + t;
    vq[q]   = rowq[q] < M_ROWS;
    ic[q] = ec[q] = 0;
    ovf[q] = eovf[q] = supp[q] = false;
  }

  // ---- classification: intra-chunk + static-window pred lists ----
#pragma unroll
  for (int q = 0; q < QRT; ++q) {
    if (!vq[q]) continue;
    const int o   = q * BLK + t;
    const int row = rowq[q];
    const int* rp = knn + (long long)row * KNN;
#pragma unroll
    for (int u = 0; u < 16; ++u) {
      int4 d = ((const int4*)rp)[u];
      int js[4] = {d.x, d.y, d.z, d.w};
#pragma unroll
      for (int m = 0; m < 4; ++m) {
        int j = js[m];
        if (j < row) {                            // strict <: ref semantics
          if (j >= base) {
            if (ic[q] < ICAP) il[ic[q]][o] = (unsigned short)(j - base);
            ++ic[q];
          } else if (j >= winb) {
            if (ec[q] < ECAP) exl[ec[q]][o] = (unsigned short)(j - winb);
            ++ec[q];
          }
          // j < winb: covered by the phase-1 reload probe
        }
      }
    }
  }
#pragma unroll
  for (int q = 0; q < QRT; ++q) {
    ovf[q]  = ic[q] > ICAP; if (ovf[q])  ic[q] = ICAP;
    eovf[q] = ec[q] > ECAP; if (eovf[q]) ec[q] = ECAP;
  }

  // ---- pre-wait: read il lists back into registers ----
  unsigned short ilr[QRT][ICAP];
#pragma unroll
  for (int q = 0; q < QRT; ++q)
#pragma unroll
    for (int x = 0; x < ICAP; ++x)
      ilr[q][x] = il[x][q * BLK + t];             // garbage beyond ic[q]: never used

  // ---- phase 1 (off-turn): trigger hint, lmq copy, deep-pred probe ----
  int praw1 = 0;
  if (b > WCH) {
    if (t < 64) {
      int pr = 0;
      for (int spin = 0; spin < (1 << 22); ++spin) {
        pr = (int)__hip_atomic_load(progress, __ATOMIC_RELAXED,
                                    __HIP_MEMORY_SCOPE_AGENT);
        if (pr >= b - WCH) break;
        __builtin_amdgcn_s_sleep(2);
      }
      if (t == 0) sh_p = (unsigned int)pr;
    }
    __syncthreads();                              // sh_p visible
    praw1 = (int)sh_p; if (praw1 > b) praw1 = b;
    const int wt = praw1 * W64PC;
    for (int w = t; w < wt; w += BLK) {           // per-word valid-spin backstop
      unsigned long long v = __hip_atomic_load(&bmg64[w], __ATOMIC_RELAXED,
                                               __HIP_MEMORY_SCOPE_AGENT);
      int g1 = 0;
      while (!(v & VALIDB) && ++g1 < (1 << 22)) {
        __builtin_amdgcn_s_sleep(1);
        v = __hip_atomic_load(&bmg64[w], __ATOMIC_RELAXED,
                              __HIP_MEMORY_SCOPE_AGENT);
      }
      lmq[w] = v;                                 // in-band valid carried over
    }
    __syncthreads();                              // lmq[0..wt) visible
    const int lim = praw1 * CHUNK;
#pragma unroll
    for (int q = 0; q < QRT; ++q)
      if (vq[q])
        supp[q] = probe_reload(knn + (long long)rowq[q] * KNN, lmq, 0, lim);
  }
  const int pr1lim = praw1 * CHUNK;
  const int ws = praw1 * W64PC;                   // words already mirrored
  const int we = b * W64PC;                       // words needed

  // ---- zero the not-yet-mirrored window words (uninit LDS = fake valid) ----
  for (int w = ws + t; w < we; w += BLK) lmq[w] = 0ull;

  // ---- build per-thread unresolved ext-pred masks ----
  unsigned int extm[QRT];
  bool eunk[QRT];
#pragma unroll
  for (int q = 0; q < QRT; ++q) {
    extm[q] = 0u; eunk[q] = false;
    if (vq[q] && !supp[q]) {
      const int o = q * BLK + t;
      const int n = ec[q];
#pragma unroll
      for (int x = 0; x < ECAP; ++x) {
        if (x < n) {
          const int j = winb + (int)exl[x][o];
          if (j >= pr1lim) extm[q] |= (1u << x);
        }
      }
      eunk[q] = eovf[q];
    }
  }

  // ---- wave-0 copy duty: each lane owns words ws+lane+64k, k=0..7 ----
  int wlist[8];
  unsigned int pw = 0u;
  if (t < 64) {
#pragma unroll
    for (int k = 0; k < 8; ++k) {
      const int w = ws + t + 64 * k;
      wlist[k] = (w < we) ? w : 0;
      if (w < we) pw |= (1u << k);
    }
  }

  // ---- st init ----
  unsigned char myst[QRT];
#pragma unroll
  for (int q = 0; q < QRT; ++q) {
    myst[q] = (!vq[q] || supp[q]) ? (unsigned char)2 : (unsigned char)0;
    __hip_atomic_store(&st[q * BLK + t], myst[q],
                       __ATOMIC_RELAXED, __HIP_MEMORY_SCOPE_WORKGROUP);
  }
  __syncthreads();                                // st + lmq zeroes visible

  // ---- merged loop: copy duty (wave 0) + decisions (all) + publish ----
  bool undec = false;
#pragma unroll
  for (int q = 0; q < QRT; ++q) undec |= (myst[q] == 0);
  bool pub_done = (b >= NCH - 1);                 // last block never publishes

  for (int pass = 0; pass < (1 << 22); ++pass) {
    bool pend = false;

    // -- wave-0 lanes: poll own pending global words, fan out into lmq --
    if (pw != 0u) {
      unsigned long long cv[8];
#pragma unroll
      for (int k = 0; k < 8; ++k) {
        const int w = ((pw >> k) & 1u) ? wlist[k] : 0;
        cv[k] = __hip_atomic_load(&bmg64[w], __ATOMIC_RELAXED,
                                  __HIP_MEMORY_SCOPE_AGENT);
      }
#pragma unroll
      for (int k = 0; k < 8; ++k) {
        if ((pw >> k) & 1u) {
          if (cv[k] & VALIDB) {
            __hip_atomic_store(&lmq[wlist[k]], cv[k],
                               __ATOMIC_RELAXED, __HIP_MEMORY_SCOPE_WORKGROUP);
            pw &= ~(1u << k);
          } else pend = true;
        }
      }
    }

    // -- decisions against LDS only --
    if (undec) {
      undec = false;
#pragma unroll
      for (int q = 0; q < QRT; ++q) {
        if (myst[q] != 0) continue;
        const int o   = q * BLK + t;
        const int row = base + o;
        bool anyK = false, allD = true;
        unsigned int m = extm[q];

        // ext preds: batched lmq (LDS) loads, two groups of 8
        if (m != 0u) {
#pragma unroll
          for (int g = 0; g < 2; ++g) {
            if ((m >> (g * 8)) & 0xffu) {
              unsigned long long ev[8];
#pragma unroll
              for (int x = 0; x < 8; ++x) {
                const int xe = g * 8 + x;
                const int j = winb + (int)exl[xe][o];
                const int w = ((m >> xe) & 1u) ? (j >> 5) : 0;
                ev[x] = __hip_atomic_load(&lmq[w], __ATOMIC_RELAXED,
                                          __HIP_MEMORY_SCOPE_WORKGROUP);
              }
#pragma unroll
              for (int x = 0; x < 8; ++x) {
                const int xe = g * 8 + x;
                if ((m >> xe) & 1u) {
                  const int j = winb + (int)exl[xe][o];
                  if (ev[x] & VALIDB) {
                    if ((ev[x] >> (j & 31)) & 1ull) anyK = true;
                    m &= ~(1u << xe);
                  } else pend = true;
                }
              }
            }
          }
          extm[q] = m;
        }

        // intra preds: batched st loads
        if (!ovf[q]) {
          unsigned char vsts[ICAP];
#pragma unroll
          for (int x = 0; x < ICAP; ++x) {
            const int ii = (x < ic[q]) ? (int)ilr[q][x] : 0;
            vsts[x] = __hip_atomic_load(&st[ii],
                __ATOMIC_RELAXED, __HIP_MEMORY_SCOPE_WORKGROUP);
          }
#pragma unroll
          for (int x = 0; x < ICAP; ++x) {
            if (x < ic[q]) { anyK |= (vsts[x] == 1); allD &= (vsts[x] != 0); }
          }
        } else {                                  // ultra-rare: rescan LDS
          const int* rp = knn + (long long)row * KNN;
#pragma unroll
          for (int u = 0; u < 16; ++u) {
            int4 d = ((const int4*)rp)[u];
            int js[4] = {d.x, d.y, d.z, d.w};
            unsigned char sv[4];
#pragma unroll
            for (int m2 = 0; m2 < 4; ++m2) {
              const bool in = (js[m2] >= base && js[m2] < row);
              sv[m2] = __hip_atomic_load(&st[in ? (js[m2] - base) : 0],
                  __ATOMIC_RELAXED, __HIP_MEMORY_SCOPE_WORKGROUP);
            }
#pragma unroll
            for (int m2 = 0; m2 < 4; ++m2) {
              if (js[m2] >= base && js[m2] < row) {
                anyK |= (sv[m2] == 1); allD &= (sv[m2] != 0);
              }
            }
          }
        }
        if (extm[q] != 0u) allD = false;

        // eovf rows (rare): full-window rescan vs lmq (LDS-only now)
        if (!anyK && eunk[q]) {
          const int lo = (pr1lim > winb) ? pr1lim : winb;
          const int* rp = knn + (long long)row * KNN;
          bool ep = false, ak = false;
#pragma unroll
          for (int g = 0; g < 8; ++g) {
            int js[8];
#pragma unroll
            for (int u = 0; u < 2; ++u) {
              int4 d = ((const int4*)rp)[g * 2 + u];
              js[u * 4 + 0] = d.x; js[u * 4 + 1] = d.y;
              js[u * 4 + 2] = d.z; js[u * 4 + 3] = d.w;
            }
            unsigned long long wv[8];
#pragma unroll
            for (int m2 = 0; m2 < 8; ++m2) {
              const bool in = (js[m2] >= lo && js[m2] < base);
              wv[m2] = __hip_atomic_load(&lmq[in ? (js[m2] >> 5) : 0],
                  __ATOMIC_RELAXED, __HIP_MEMORY_SCOPE_WORKGROUP);
            }
#pragma unroll
            for (int m2 = 0; m2 < 8; ++m2) {
              if (js[m2] >= lo && js[m2] < base) {
                if (wv[m2] & VALIDB) { if ((wv[m2] >> (js[m2] & 31)) & 1ull) ak = true; }
                else ep = true;
              }
            }
          }
          if (ak) anyK = true;
          else if (!ep) eunk[q] = false;
          if (ep) pend = true;
        }
        if (eunk[q]) allD = false;

        if (anyK)      myst[q] = 2;
        else if (allD) myst[q] = 1;
        if (myst[q] != 0)
          __hip_atomic_store(&st[o], myst[q],
                             __ATOMIC_RELAXED, __HIP_MEMORY_SCOPE_WORKGROUP);
        else
          undec = true;
      }
    }

    // -- per-wave publish the moment all 64 lanes decided --
    unsigned long long wdone = __ballot(!undec);
    if (!pub_done && wdone == ~0ull) {
      const int lane = t & 63;
      bool kq0[QRT];
#pragma unroll
      for (int q = 0; q < QRT; ++q)
        kq0[q] = vq[q] && (myst[q] == 1);
#pragma unroll
      for (int q = 0; q < QRT; ++q) {
        unsigned long long ba = __ballot(kq0[q]);
        const int g = b * W64PC + ((q * BLK + (t & ~63)) >> 5);
        if (lane == 0)
          __hip_atomic_store(&bmg64[g], (ba & 0xffffffffull) | VALIDB,
                             __ATOMIC_RELAXED, __HIP_MEMORY_SCOPE_AGENT);
        if (lane == 32)
          __hip_atomic_store(&bmg64[g + 1], (ba >> 32) | VALIDB,
                             __ATOMIC_RELAXED, __HIP_MEMORY_SCOPE_AGENT);
      }
      pub_done = true;
    }

    // -- wave-uniform exit: loop while any lane undecided or copying --
    const bool mustloop = undec || (pw != 0u);
    if (__ballot(mustloop) == 0ull) break;
    if (pend) __builtin_amdgcn_s_sleep(1);        // throttle polls
  }

  __syncthreads();                                // all waves done + published
  if (t == 0)                                     // hint for phase-1 triggers
    __hip_atomic_store(progress, (unsigned int)(b + 1),
                       __ATOMIC_RELAXED, __HIP_MEMORY_SCOPE_AGENT);

  // ---- outputs (off the chain; block 73's knn overwrites dead scratch) ----
  bool kq[QRT];
#pragma unroll
  for (int q = 0; q < QRT; ++q)
    kq[q] = vq[q] && (myst[q] == 1);

#pragma unroll
  for (int q = 0; q < QRT; ++q)
    if (vq[q]) out[rowq[q]] = kq[q] ? 1 : 0;

#pragma unroll
  for (int q = 0; q < QRT; ++q) {
    if (!vq[q]) continue;
    const int row = rowq[q];
    const int* rp = knn + (long long)row * KNN;
    int* orow = out + M_ROWS + (long long)row * KNN;
    const bool k = kq[q];
#pragma unroll
    for (int u = 0; u < 16; ++u) {
      int4 d = ((const int4*)rp)[u];
      int4 o4;
      o4.x = k ? d.x : M_ROWS;
      o4.y = k ? d.y : M_ROWS;
      o4.z = k ? d.z : M_ROWS;
      o4.w = k ? d.w : M_ROWS;
      ((int4*)orow)[u] = o4;
    }
  }
}

extern "C" void kernel_launch(void* const* d_in, const int* in_sizes, int n_in,
                              void* d_out, int out_size, void* d_ws, size_t ws_size,
                              hipStream_t stream) {
  const int* knn = (const int*)d_in[1];
  int* out = (int*)d_out;
  unsigned int* progress = (unsigned int*)d_ws;

  init_ws_kernel<<<(NBMG + BLK - 1) / BLK, BLK, 0, stream>>>(progress, out);
  nms_chain_kernel<<<NCH, BLK, 0, stream>>>(knn, out, progress);
}

// Round 13
// 375.969 us; speedup vs baseline: 1.2297x; 1.2297x over previous
//
#include <hip/hip_runtime.h>

// Greedy NMS: keep[i] = !any(keep[j] for j in knn[i] if j < i)
//
// Round-25: per-row decided bits IN the word channel (R21 base).
// R23/R24 (byte channel) both died in the harness with burst width
// controlled for -> abandon that channel. Same goal, validated envelope:
//   - word encoding: (decided_mask << 32) | kept_mask  (2 bits/row).
//     Consumers check the PRED'S OWN decided bit (no whole-word valid,
//     no wave-slowest-lane gating). Phase-1 bulk copy waits for
//     decided==0xFFFFFFFF (same spin structure as R21's VALIDB).
//   - producers REPUBLISH their wave's words whenever the wave's
//     decided-ballot changes (ballot-compare gates the store -> store
//     traffic ~ #decisions). First publish right after st-init, where
//     ~96% of rows are already decided (phase-1 supp + trivial kept).
//   - st-init kept fast path: ic==0 && !ovf && extm==0 && !eunk
//     (extm built BEFORE st init).
//   - 2 extra LDS-only intra sweeps per pass (collapse intra levels).
//   - pass loop made wave-uniform (ballots must see all 64 lanes).
// Poll addresses / widths (<=8) / rates identical to R21 (passed 2x).
// Geometry: CHUNK=2048, QRT=2, NCH=74, WCH=8, ICAP=6, ECAP=16.
//
// Output encoding (validated round 4): INT32.
//   d_out[0..M)        : kept flags, 1 / 0
//   d_out[M..M+M*64)   : kept_knn, idx or 150000 (tail doubles as u64 word
//                        scratch, owned by block 73 which never publishes)
// d_ws[0..3]: progress counter (zeroed by init kernel each call)

#define M_ROWS 150000
#define KNN    64
#define BLK    1024
#define QRT    2
#define CHUNK  (BLK * QRT)                        // 2048
#define NCH    ((M_ROWS + CHUNK - 1) / CHUNK)     // 74
#define ICAP   6
#define ECAP   16
#define WCH    8                                  // exl window, chunks (16384 rows)
#define W64PC  (CHUNK / 32)                       // 64 published u64 words/chunk
#define LMW    (((NCH - 1) * CHUNK) / 32)         // 4672 u32 mirror words
#define NBMG   ((NCH - 1) * W64PC)                // 4672 published u64 words
#define OUT_INTS (M_ROWS + M_ROWS * KNN)
#define BMG_INT_OFF (OUT_INTS - NBMG * 2)         // 8B-aligned; rows >= 149854
#define DECFULL 0xffffffffu

__global__ void init_ws_kernel(unsigned int* progress, int* out) {
  const int i = blockIdx.x * blockDim.x + threadIdx.x;
  unsigned long long* bmg64 = (unsigned long long*)(out + BMG_INT_OFF);
  if (i < NBMG) bmg64[i] = 0ull;                  // decided=0, kept=0
  if (i == 0) *progress = 0u;
}

// reload a row and probe preds j in [lo, hi) against the LDS kept-bitmask
__device__ __forceinline__ bool probe_reload(const int* __restrict__ rp,
                                             const unsigned int* lm,
                                             int lo, int hi) {
  bool s = false;
#pragma unroll
  for (int u = 0; u < 16; ++u) {
    int4 d = ((const int4*)rp)[u];
    int js[4] = {d.x, d.y, d.z, d.w};
#pragma unroll
    for (int m = 0; m < 4; ++m) {
      int j = js[m];
      if (j >= lo && j < hi && ((lm[j >> 5] >> (j & 31)) & 1u)) s = true;
    }
  }
  return s;
}

__global__ __launch_bounds__(BLK) void nms_chain_kernel(
    const int* __restrict__ knn,
    int* __restrict__ out,
    unsigned int* __restrict__ progress)
{
  const int b    = blockIdx.x;
  const int t    = threadIdx.x;
  const int base = b * CHUNK;
  const int winb = (b > WCH) ? (base - WCH * CHUNK) : 0;   // exl window base

  unsigned long long* bmg64 = (unsigned long long*)(out + BMG_INT_OFF);

  __shared__ unsigned char      st[CHUNK];        // 0 unk, 1 kept, 2 supp
  __shared__ unsigned short     il[ICAP][CHUNK];  // TRANSPOSED: conflict-free
  __shared__ unsigned short     exl[ECAP][CHUNK]; // TRANSPOSED: conflict-free
  __shared__ unsigned int       lm[LMW];          // mirrored keep bits
  __shared__ unsigned int       sh_p;

  int  rowq[QRT];
  bool vq[QRT], ovf[QRT], eovf[QRT], supp[QRT];
  int  ic[QRT], ec[QRT];

#pragma unroll
  for (int q = 0; q < QRT; ++q) {
    rowq[q] = base + q * BLK + t;
    vq[q]   = rowq[q] < M_ROWS;
    ic[q] = ec[q] = 0;
    ovf[q] = eovf[q] = supp[q] = false;
  }

  // ---- classification: intra-chunk + static-window pred lists ----
#pragma unroll
  for (int q = 0; q < QRT; ++q) {
    if (!vq[q]) continue;
    const int o   = q * BLK + t;
    const int row = rowq[q];
    const int* rp = knn + (long long)row * KNN;
#pragma unroll
    for (int u = 0; u < 16; ++u) {
      int4 d = ((const int4*)rp)[u];
      int js[4] = {d.x, d.y, d.z, d.w};
#pragma unroll
      for (int m = 0; m < 4; ++m) {
        int j = js[m];
        if (j < row) {                            // strict <: ref semantics
          if (j >= base) {
            if (ic[q] < ICAP) il[ic[q]][o] = (unsigned short)(j - base);
            ++ic[q];
          } else if (j >= winb) {
            if (ec[q] < ECAP) exl[ec[q]][o] = (unsigned short)(j - winb);
            ++ec[q];
          }
          // j < winb: covered by the phase-1 reload probe
        }
      }
    }
  }
#pragma unroll
  for (int q = 0; q < QRT; ++q) {
    ovf[q]  = ic[q] > ICAP; if (ovf[q])  ic[q] = ICAP;
    eovf[q] = ec[q] > ECAP; if (eovf[q]) ec[q] = ECAP;
  }

  // ---- pre-wait: read il lists back into registers ----
  unsigned short ilr[QRT][ICAP];
#pragma unroll
  for (int q = 0; q < QRT; ++q)
#pragma unroll
    for (int x = 0; x < ICAP; ++x)
      ilr[q][x] = il[x][q * BLK + t];             // garbage beyond ic[q]: never used

  // ---- phase 1 (off-turn): trigger hint, lm copy, deep-pred probe ----
  int praw1 = 0;
  if (b > WCH) {
    if (t < 64) {
      int pr = 0;
      for (int spin = 0; spin < (1 << 22); ++spin) {
        pr = (int)__hip_atomic_load(progress, __ATOMIC_RELAXED,
                                    __HIP_MEMORY_SCOPE_AGENT);
        if (pr >= b - WCH) break;
        __builtin_amdgcn_s_sleep(2);
      }
      if (t == 0) sh_p = (unsigned int)pr;
    }
    __syncthreads();                              // sh_p visible
    praw1 = (int)sh_p; if (praw1 > b) praw1 = b;
    const int wt = praw1 * W64PC;
    for (int w = t; w < wt; w += BLK) {           // spin: word fully decided
      unsigned long long v = __hip_atomic_load(&bmg64[w], __ATOMIC_RELAXED,
                                               __HIP_MEMORY_SCOPE_AGENT);
      int g1 = 0;
      while (((unsigned int)(v >> 32)) != DECFULL && ++g1 < (1 << 22)) {
        __builtin_amdgcn_s_sleep(1);
        v = __hip_atomic_load(&bmg64[w], __ATOMIC_RELAXED,
                              __HIP_MEMORY_SCOPE_AGENT);
      }
      lm[w] = (unsigned int)v;                    // kept mask (low 32)
    }
    __syncthreads();                              // lm visible
    const int lim = praw1 * CHUNK;
#pragma unroll
    for (int q = 0; q < QRT; ++q)
      if (vq[q])
        supp[q] = probe_reload(knn + (long long)rowq[q] * KNN, lm, 0, lim);
  }
  const int pr1lim = praw1 * CHUNK;

  // ---- build per-thread unresolved ext-pred masks (BEFORE st init) ----
  unsigned int extm[QRT];
  bool eunk[QRT];
#pragma unroll
  for (int q = 0; q < QRT; ++q) {
    extm[q] = 0u; eunk[q] = false;
    if (vq[q] && !supp[q]) {
      const int o = q * BLK + t;
      const int n = ec[q];
#pragma unroll
      for (int x = 0; x < ECAP; ++x) {
        if (x < n) {
          const int j = winb + (int)exl[x][o];
          if (j >= pr1lim) extm[q] |= (1u << x);
        }
      }
      eunk[q] = eovf[q];
    }
  }

  // ---- st init with kept fast path ----
  unsigned char myst[QRT];
#pragma unroll
  for (int q = 0; q < QRT; ++q) {
    myst[q] = (!vq[q] || supp[q]) ? (unsigned char)2
            : ((ic[q] == 0 && !ovf[q] && extm[q] == 0u && !eunk[q])
               ? (unsigned char)1 : (unsigned char)0);
    __hip_atomic_store(&st[q * BLK + t], myst[q],
                       __ATOMIC_RELAXED, __HIP_MEMORY_SCOPE_WORKGROUP);
  }
  __syncthreads();                                // st init visible to all waves

  // ---- initial publish: ~96% of rows already decided ----
  const int lane = t & 63;
  unsigned long long lastd[QRT];
#pragma unroll
  for (int q = 0; q < QRT; ++q) lastd[q] = 0ull;
  if (b < NCH - 1) {
#pragma unroll
    for (int q = 0; q < QRT; ++q) {
      unsigned long long bdec  = __ballot(myst[q] != 0);
      unsigned long long bkept = __ballot(myst[q] == 1);
      const int g = b * W64PC + ((q * BLK + (t & ~63)) >> 5);
      if (lane == 0)
        __hip_atomic_store(&bmg64[g],
            ((bdec & 0xffffffffull) << 32) | (bkept & 0xffffffffull),
            __ATOMIC_RELAXED, __HIP_MEMORY_SCOPE_AGENT);
      if (lane == 32)
        __hip_atomic_store(&bmg64[g + 1],
            ((bdec >> 32) << 32) | (bkept >> 32),
            __ATOMIC_RELAXED, __HIP_MEMORY_SCOPE_AGENT);
      lastd[q] = bdec;
    }
  }

  bool undec = false;
#pragma unroll
  for (int q = 0; q < QRT; ++q) undec |= (myst[q] == 0);

  // ---- wave-uniform dataflow loop ----
  for (int pass = 0; pass < (1 << 22); ++pass) {
    bool pend = false;
    if (undec) {
#pragma unroll
      for (int q = 0; q < QRT; ++q) {
        if (myst[q] != 0) continue;
        const int o   = q * BLK + t;
        const int row = base + o;
        bool anyK = false, allD = true;
        unsigned int m = extm[q];

        // ext preds: batches of 8; per-row decided bit (hi32), kept (lo32)
        if (m != 0u) {
#pragma unroll
          for (int g = 0; g < 2; ++g) {
            if ((m >> (g * 8)) & 0xffu) {
              unsigned long long vv[8];
#pragma unroll
              for (int x = 0; x < 8; ++x) {
                const int xe = g * 8 + x;
                const int j = winb + (int)exl[xe][o];
                const int w = ((m >> xe) & 1u) ? (j >> 5) : 0;
                vv[x] = __hip_atomic_load(&bmg64[w], __ATOMIC_RELAXED,
                                          __HIP_MEMORY_SCOPE_AGENT);
              }
#pragma unroll
              for (int x = 0; x < 8; ++x) {
                const int xe = g * 8 + x;
                if ((m >> xe) & 1u) {
                  const int j = winb + (int)exl[xe][o];
                  const int bit = j & 31;
                  if ((((unsigned int)(vv[x] >> 32)) >> bit) & 1u) {
                    if ((((unsigned int)vv[x]) >> bit) & 1u) anyK = true;
                    m &= ~(1u << xe);
                  } else pend = true;
                }
              }
            }
          }
          extm[q] = m;
        }

        // intra preds: batched LDS loads
        if (!ovf[q]) {
          unsigned char vsts[ICAP];
#pragma unroll
          for (int x = 0; x < ICAP; ++x) {
            const int ii = (x < ic[q]) ? (int)ilr[q][x] : 0;
            vsts[x] = __hip_atomic_load(&st[ii],
                __ATOMIC_RELAXED, __HIP_MEMORY_SCOPE_WORKGROUP);
          }
#pragma unroll
          for (int x = 0; x < ICAP; ++x) {
            if (x < ic[q]) { anyK |= (vsts[x] == 1); allD &= (vsts[x] != 0); }
          }
        } else {                                  // ultra-rare: rescan LDS
          const int* rp = knn + (long long)row * KNN;
#pragma unroll
          for (int u = 0; u < 16; ++u) {
            int4 d = ((const int4*)rp)[u];
            int js[4] = {d.x, d.y, d.z, d.w};
            unsigned char sv[4];
#pragma unroll
            for (int m2 = 0; m2 < 4; ++m2) {
              const bool in = (js[m2] >= base && js[m2] < row);
              sv[m2] = __hip_atomic_load(&st[in ? (js[m2] - base) : 0],
                  __ATOMIC_RELAXED, __HIP_MEMORY_SCOPE_WORKGROUP);
            }
#pragma unroll
            for (int m2 = 0; m2 < 4; ++m2) {
              if (js[m2] >= base && js[m2] < row) {
                anyK |= (sv[m2] == 1); allD &= (sv[m2] != 0);
              }
            }
          }
        }
        if (extm[q] != 0u) allD = false;

        // eovf rows (rare): full-window rescan, per-row decided bits
        if (!anyK && eunk[q]) {
          const int lo = (pr1lim > winb) ? pr1lim : winb;
          const int* rp = knn + (long long)row * KNN;
          bool ep = false, ak = false;
#pragma unroll
          for (int g = 0; g < 8; ++g) {
            int js[8];
#pragma unroll
            for (int u = 0; u < 2; ++u) {
              int4 d = ((const int4*)rp)[g * 2 + u];
              js[u * 4 + 0] = d.x; js[u * 4 + 1] = d.y;
              js[u * 4 + 2] = d.z; js[u * 4 + 3] = d.w;
            }
            unsigned long long wv[8];
#pragma unroll
            for (int m2 = 0; m2 < 8; ++m2) {
              const bool in = (js[m2] >= lo && js[m2] < base);
              wv[m2] = __hip_atomic_load(&bmg64[in ? (js[m2] >> 5) : 0],
                  __ATOMIC_RELAXED, __HIP_MEMORY_SCOPE_AGENT);
            }
#pragma unroll
            for (int m2 = 0; m2 < 8; ++m2) {
              if (js[m2] >= lo && js[m2] < base) {
                const int bit = js[m2] & 31;
                if ((((unsigned int)(wv[m2] >> 32)) >> bit) & 1u) {
                  if ((((unsigned int)wv[m2]) >> bit) & 1u) ak = true;
                } else ep = true;
              }
            }
          }
          if (ak) anyK = true;
          else if (!ep) eunk[q] = false;
          if (ep) pend = true;
        }
        if (eunk[q]) allD = false;

        if (anyK)      myst[q] = 2;
        else if (allD) myst[q] = 1;
        if (myst[q] != 0)
          __hip_atomic_store(&st[o], myst[q],
                             __ATOMIC_RELAXED, __HIP_MEMORY_SCOPE_WORKGROUP);
      }

      // 2 extra LDS-only intra sweeps: collapse intra chain levels
#pragma unroll
      for (int s = 0; s < 2; ++s) {
#pragma unroll
        for (int q = 0; q < QRT; ++q) {
          if (myst[q] != 0 || ovf[q]) continue;
          const int o = q * BLK + t;
          bool anyK = false, allD = true;
          unsigned char vsts[ICAP];
#pragma unroll
          for (int x = 0; x < ICAP; ++x) {
            const int ii = (x < ic[q]) ? (int)ilr[q][x] : 0;
            vsts[x] = __hip_atomic_load(&st[ii],
                __ATOMIC_RELAXED, __HIP_MEMORY_SCOPE_WORKGROUP);
          }
#pragma unroll
          for (int x = 0; x < ICAP; ++x) {
            if (x < ic[q]) { anyK |= (vsts[x] == 1); allD &= (vsts[x] != 0); }
          }
          if (extm[q] != 0u || eunk[q]) allD = false;
          if (anyK)      myst[q] = 2;
          else if (allD) myst[q] = 1;
          if (myst[q] != 0)
            __hip_atomic_store(&st[o], myst[q],
                               __ATOMIC_RELAXED, __HIP_MEMORY_SCOPE_WORKGROUP);
        }
      }

      undec = false;
#pragma unroll
      for (int q = 0; q < QRT; ++q) undec |= (myst[q] == 0);
    }

    // ---- change-gated republish (all lanes active here) ----
    if (b < NCH - 1) {
#pragma unroll
      for (int q = 0; q < QRT; ++q) {
        unsigned long long bdec = __ballot(myst[q] != 0);
        if (bdec != lastd[q]) {
          unsigned long long bkept = __ballot(myst[q] == 1);
          const int g = b * W64PC + ((q * BLK + (t & ~63)) >> 5);
          if (lane == 0)
            __hip_atomic_store(&bmg64[g],
                ((bdec & 0xffffffffull) << 32) | (bkept & 0xffffffffull),
                __ATOMIC_RELAXED, __HIP_MEMORY_SCOPE_AGENT);
          if (lane == 32)
            __hip_atomic_store(&bmg64[g + 1],
                ((bdec >> 32) << 32) | (bkept >> 32),
                __ATOMIC_RELAXED, __HIP_MEMORY_SCOPE_AGENT);
          lastd[q] = bdec;
        }
      }
    }

    if (__ballot(undec) == 0ull) break;           // wave-uniform exit
    if (__ballot(pend) != 0ull) __builtin_amdgcn_s_sleep(1);
  }

  __syncthreads();                                // all waves done + published
  if (t == 0)                                     // hint for phase-1 triggers
    __hip_atomic_store(progress, (unsigned int)(b + 1),
                       __ATOMIC_RELAXED, __HIP_MEMORY_SCOPE_AGENT);

  // ---- outputs (off the chain; block 73's knn overwrites dead scratch) ----
  bool kq[QRT];
#pragma unroll
  for (int q = 0; q < QRT; ++q)
    kq[q] = vq[q] && (myst[q] == 1);

#pragma unroll
  for (int q = 0; q < QRT; ++q)
    if (vq[q]) out[rowq[q]] = kq[q] ? 1 : 0;

#pragma unroll
  for (int q = 0; q < QRT; ++q) {
    if (!vq[q]) continue;
    const int row = rowq[q];
    const int* rp = knn + (long long)row * KNN;
    int* orow = out + M_ROWS + (long long)row * KNN;
    const bool k = kq[q];
#pragma unroll
    for (int u = 0; u < 16; ++u) {
      int4 d = ((const int4*)rp)[u];
      int4 o4;
      o4.x = k ? d.x : M_ROWS;
      o4.y = k ? d.y : M_ROWS;
      o4.z = k ? d.z : M_ROWS;
      o4.w = k ? d.w : M_ROWS;
      ((int4*)orow)[u] = o4;
    }
  }
}

extern "C" void kernel_launch(void* const* d_in, const int* in_sizes, int n_in,
                              void* d_out, int out_size, void* d_ws, size_t ws_size,
                              hipStream_t stream) {
  const int* knn = (const int*)d_in[1];
  int* out = (int*)d_out;
  unsigned int* progress = (unsigned int*)d_ws;

  init_ws_kernel<<<(NBMG + BLK - 1) / BLK, BLK, 0, stream>>>(progress, out);
  nms_chain_kernel<<<NCH, BLK, 0, stream>>>(knn, out, progress);
}